// Round 20
// baseline (201.682 us; speedup 1.0000x reference)
//
#include <hip/hip_runtime.h>

typedef unsigned short u16;
typedef unsigned int u32;
typedef unsigned long long u64;
typedef __bf16 bf16x8 __attribute__((ext_vector_type(8)));
typedef float f32x4 __attribute__((ext_vector_type(4)));

#define B_ 4
#define N_ 2048
#define D_ 1024
#define H_ 16
#define DH_ 64
#define NKP_ 2112   // padded key slots: 33*64.  slots 0..2047 = seq keys,
#define NKT_ 33     // slot 2048 = null kv (always visible), 2049+ = zero pad

__device__ __forceinline__ float bf2f(u16 u) {
  union { u32 i; float f; } v; v.i = ((u32)u) << 16; return v.f;
}
__device__ __forceinline__ u16 f2bf(float f) {
  union { float f; u32 i; } v; v.f = f;
  u32 r = v.i + 0x7fffu + ((v.i >> 16) & 1u);
  return (u16)(r >> 16);
}
__device__ __forceinline__ u32 cvtpk(float a, float b) {  // {lo=bf16(a), hi=bf16(b)}
  u32 r;
  asm("v_cvt_pk_bf16_f32 %0, %1, %2" : "=v"(r) : "v"(a), "v"(b));
  return r;
}
__device__ __forceinline__ void load_lds16(const void* g, void* l) {
  __builtin_amdgcn_global_load_lds((const __attribute__((address_space(1))) void*)g,
                                   (__attribute__((address_space(3))) void*)l, 16, 0, 0);
}

// ---------------- LayerNorm: x f32 [8192][1024] -> xn bf16 ----------------
__global__ __launch_bounds__(256) void ln_kernel(const float* __restrict__ x,
                                                 const float* __restrict__ gamma,
                                                 u16* __restrict__ xn) {
  int row = blockIdx.x;
  int tid = threadIdx.x, lane = tid & 63, wid = tid >> 6;
  const float4 v = ((const float4*)(x + (size_t)row * D_))[tid];
  float s  = v.x + v.y + v.z + v.w;
  float ss = v.x * v.x + v.y * v.y + v.z * v.z + v.w * v.w;
#pragma unroll
  for (int off = 1; off < 64; off <<= 1) {
    s  += __shfl_xor(s,  off, 64);
    ss += __shfl_xor(ss, off, 64);
  }
  __shared__ float rs[4], rss[4];
  if (lane == 0) { rs[wid] = s; rss[wid] = ss; }
  __syncthreads();
  float S  = rs[0] + rs[1] + rs[2] + rs[3];
  float SS = rss[0] + rss[1] + rss[2] + rss[3];
  float mean = S * (1.0f / D_);
  float var  = SS * (1.0f / D_) - mean * mean;
  float inv  = rsqrtf(var + 1e-5f);
  const float4 g = ((const float4*)gamma)[tid];
  ushort4 o;
  o.x = f2bf((v.x - mean) * inv * g.x);
  o.y = f2bf((v.y - mean) * inv * g.y);
  o.z = f2bf((v.z - mean) * inv * g.z);
  o.w = f2bf((v.w - mean) * inv * g.w);
  *(ushort4*)(xn + (size_t)row * D_ + tid * 4) = o;
}

// ------- merged weight transpose+cast: {wq, wkv, wo} in ONE launch -------
__global__ __launch_bounds__(256) void wt3_kernel(const float* __restrict__ wq,
                                                  const float* __restrict__ wkv,
                                                  const float* __restrict__ wo,
                                                  u16* __restrict__ wqkvT,
                                                  u16* __restrict__ woT) {
  int t = blockIdx.x;
  const float* W;
  u16* WT;
  int N, tile;
  if (t < 1024)      { W = wq;  WT = wqkvT;                N = 1024; tile = t; }
  else if (t < 3072) { W = wkv; WT = wqkvT + 1024 * 1024;  N = 2048; tile = t - 1024; }
  else               { W = wo;  WT = woT;                  N = 1024; tile = t - 3072; }
  __shared__ float tb[32][33];
  int tiles_n = N >> 5;
  int tk = tile / tiles_n, tn = tile % tiles_n;
  int tx = threadIdx.x & 31, ty = threadIdx.x >> 5;  // ty in [0,8)
  int k0 = tk << 5, n0 = tn << 5;
#pragma unroll
  for (int i = 0; i < 4; ++i)
    tb[ty + i * 8][tx] = W[(size_t)(k0 + ty + i * 8) * N + n0 + tx];
  __syncthreads();
#pragma unroll
  for (int i = 0; i < 4; ++i)
    WT[(size_t)(n0 + ty + i * 8) * 1024 + k0 + tx] = f2bf(tb[tx][ty + i * 8]);
}

// ------------- prep: null KV row, zero pads, masked-key counts, softmax shift ----
__global__ __launch_bounds__(256) void prep_kernel(const int* __restrict__ mask,
                                                   const float* __restrict__ qs,
                                                   const float* __restrict__ ksc,
                                                   const float* __restrict__ null_kv,
                                                   u16* __restrict__ Kb,
                                                   u16* __restrict__ Vt,
                                                   float* __restrict__ cb) {
  __shared__ int cnts[4];
  int bh = blockIdx.x, h = bh & 15;
  int tid = threadIdx.x, lane = tid & 63, wid = tid >> 6;
  if (wid == 0) {
    float kv = null_kv[h * 64 + lane];
    float ss = kv * kv;
#pragma unroll
    for (int off = 1; off < 64; off <<= 1) ss += __shfl_xor(ss, off, 64);
    float inv = 1.0f / fmaxf(sqrtf(ss), 1e-12f);
    Kb[((size_t)bh * NKP_ + 2048) * 64 + lane] = f2bf(kv * inv * ksc[lane]);
    Vt[((size_t)bh * 64 + lane) * NKP_ + 2048] = f2bf(null_kv[1024 + h * 64 + lane]);
  }
  for (int i = tid; i < 63 * 64; i += 256) {  // Kb pad rows 2049..2111
    int r = i >> 6, c = i & 63;
    Kb[((size_t)bh * NKP_ + 2049 + r) * 64 + c] = 0;
  }
  for (int i = tid; i < 64 * 63; i += 256) {  // Vt pad cols 2049..2111
    int d = i / 63, c = i % 63;
    Vt[((size_t)bh * 64 + d) * NKP_ + 2049 + c] = 0;
  }
  if (bh == 0) {
    if (tid < 4) cnts[tid] = 0;
    __syncthreads();
    int c0 = 0, c1 = 0, c2 = 0, c3 = 0;
    for (int i = tid; i < B_ * N_; i += 256) {
      int z = (mask[i] == 0);
      int b = i >> 11;
      if (b == 0) c0 += z; else if (b == 1) c1 += z; else if (b == 2) c2 += z; else c3 += z;
    }
    atomicAdd(&cnts[0], c0); atomicAdd(&cnts[1], c1);
    atomicAdd(&cnts[2], c2); atomicAdd(&cnts[3], c3);
    __syncthreads();
    if (tid == 0) {
      float mw = 0.f;
      for (int i = 0; i < DH_; ++i) mw = fmaxf(mw, fabsf(qs[i] * ksc[i]));
      float cbias = -8.0f * mw * 1.4426950408889634f;
      cb[0] = cbias;
      float e = __builtin_amdgcn_exp2f(cbias);  // same HW instr as attn's exp2
#pragma unroll
      for (int b = 0; b < 4; ++b) cb[1 + b] = (float)(cnts[b] + 63) * e;
    }
  }
}

// ------------- fused QKV GEMM, 256x256 tile, 8 waves, dbuf 128 KB LDS -------------
// MEASURED-BEST (R10/R16/R18: ~104.5 us).  Design space closed: blocking
// 1-tile 104.8 / counted 1-deep 108 / counted 3-deep 108-111 / 2blk-TLP 108.9
// / blocking 2-tile 114.5.  Binder = staging drain; escape needs the full
// m201 8-phase interleave (out of headless risk budget, m196/m152).
__global__ __launch_bounds__(512, 1) void gemm_qkv(const u16* __restrict__ A,
                                                   const u16* __restrict__ Bt,
                                                   u16* __restrict__ Qo,
                                                   u16* __restrict__ Kb,
                                                   u16* __restrict__ Vt,
                                                   const float* __restrict__ qs,
                                                   const float* __restrict__ ksc,
                                                   const int* __restrict__ Mask) {
  __shared__ __attribute__((aligned(16))) u16 dsm[65536];  // 128 KB: [buf][A|B][256*64]
  int bx = blockIdx.x, by = blockIdx.y;
  int tid = threadIdx.x, lane = tid & 63, wid = tid >> 6;  // wid 0..7
  int wr = wid >> 2, wc = wid & 3;
  int m0 = bx * 256, n0 = by * 256;
  int wm = wr * 128, wn = wc * 64;
  int la = lane & 15, hi = lane >> 4, crow = hi * 4;
  int sr = lane >> 3;
  int scz = ((lane & 7) ^ (lane >> 3)) * 8;  // pre-swizzled source column (elems)
  f32x4 acc[8][4] = {};

#define QSTAGE(buf, kt)                                                        \
  do {                                                                         \
    int k0_ = (kt) * 64;                                                       \
    u16* ab_ = dsm + (buf) * 32768;                                            \
    _Pragma("unroll")                                                          \
    for (int r4 = 0; r4 < 4; ++r4) {                                           \
      int r_ = r4 * 64 + wid * 8;       /* wave-uniform row base */            \
      load_lds16(A  + (size_t)(m0 + r_ + sr) * 1024 + k0_ + scz, ab_ + r_ * 64); \
      load_lds16(Bt + (size_t)(n0 + r_ + sr) * 1024 + k0_ + scz, ab_ + 16384 + r_ * 64); \
    }                                                                          \
  } while (0)

  QSTAGE(0, 0);

  for (int kt = 0; kt < 16; ++kt) {
    int buf = kt & 1;
    __syncthreads();  // drains vmcnt: tile kt present; tile kt-1 fully consumed
    if (kt + 1 < 16) QSTAGE(buf ^ 1, kt + 1);
    const u16* a_l = dsm + buf * 32768;
    const u16* b_l = a_l + 16384;
    __builtin_amdgcn_s_setprio(1);
#pragma unroll
    for (int s = 0; s < 2; ++s) {
      int slotbase = s * 4 + hi;  // k-group; LDS slot = group ^ (row&7), row&7 = la&7
      bf16x8 bfr[4];
#pragma unroll
      for (int nf = 0; nf < 4; ++nf)
        bfr[nf] = *(const bf16x8*)&b_l[(wn + nf * 16 + la) * 64 + ((slotbase ^ (la & 7)) * 8)];
#pragma unroll
      for (int mf = 0; mf < 8; ++mf) {
        bf16x8 af = *(const bf16x8*)&a_l[(wm + mf * 16 + la) * 64 + ((slotbase ^ (la & 7)) * 8)];
#pragma unroll
        for (int nf = 0; nf < 4; ++nf)
          acc[mf][nf] = __builtin_amdgcn_mfma_f32_16x16x32_bf16(af, bfr[nf], acc[mf][nf], 0, 0, 0);
      }
    }
    __builtin_amdgcn_s_setprio(0);
  }
#undef QSTAGE

  int ccol = la;
  if (by < 4) {
    // ---- q: fused per-head l2norm * qs (wave cols = one head) ----
    float qsv[4];
#pragma unroll
    for (int nf = 0; nf < 4; ++nf) qsv[nf] = qs[nf * 16 + ccol];
#pragma unroll
    for (int mf = 0; mf < 8; ++mf) {
      float invr[4];
#pragma unroll
      for (int r = 0; r < 4; ++r) {
        float ss = 0.f;
#pragma unroll
        for (int nf = 0; nf < 4; ++nf) ss += acc[mf][nf][r] * acc[mf][nf][r];
#pragma unroll
        for (int off = 1; off < 16; off <<= 1) ss += __shfl_xor(ss, off, 64);
        invr[r] = 1.0f / fmaxf(sqrtf(ss), 1e-12f);
      }
#pragma unroll
      for (int nf = 0; nf < 4; ++nf) {
        int rr = m0 + wm + mf * 16 + crow;
        int cc = by * 256 + wn + nf * 16 + ccol;
#pragma unroll
        for (int r = 0; r < 4; ++r)
          Qo[(size_t)(rr + r) * 1024 + cc] = f2bf(acc[mf][nf][r] * invr[r] * qsv[nf]);
      }
    }
    return;
  }

  int rr0 = m0 + wm;          // wave's 128 rows; never crosses batch boundary
  int b = rr0 >> 11;
  int seq0 = rr0 & 2047;
  const int* mrow = Mask + b * N_ + seq0;
  if (by < 8) {
    // ---- K: fused l2norm * ksc, masked rows zeroed -> Kb[bh][key][64] ----
    int h = (by - 4) * 4 + wc;
    float kscv[4];
#pragma unroll
    for (int nf = 0; nf < 4; ++nf) kscv[nf] = ksc[nf * 16 + ccol];
    u16* kb = Kb + ((size_t)(b * 16 + h) * NKP_) * 64;
#pragma unroll
    for (int mf = 0; mf < 8; ++mf) {
      float invr[4]; int mvv[4];
#pragma unroll
      for (int r = 0; r < 4; ++r) {
        float ss = 0.f;
#pragma unroll
        for (int nf = 0; nf < 4; ++nf) ss += acc[mf][nf][r] * acc[mf][nf][r];
#pragma unroll
        for (int off = 1; off < 16; off <<= 1) ss += __shfl_xor(ss, off, 64);
        invr[r] = 1.0f / fmaxf(sqrtf(ss), 1e-12f);
        mvv[r] = mrow[mf * 16 + crow + r];  // row-uniform -> broadcast load
      }
#pragma unroll
      for (int nf = 0; nf < 4; ++nf)
#pragma unroll
        for (int r = 0; r < 4; ++r)
          kb[(size_t)(seq0 + mf * 16 + crow + r) * 64 + nf * 16 + ccol] =
              f2bf(mvv[r] ? acc[mf][nf][r] * invr[r] * kscv[nf] : 0.f);
    }
  } else {
    // ---- V: mask-zero, transpose 128key x 64d wave tile via LDS -> Vt ----
    int h = (by - 8) * 4 + wc;
    __syncthreads();                 // all waves done reading gemm tiles
    u16* tw = dsm + wid * 8192;      // per-wave [64 d][128 key], key-slot swizzled
#pragma unroll
    for (int mf = 0; mf < 8; ++mf) {
      int mvv[4];
#pragma unroll
      for (int r = 0; r < 4; ++r) mvv[r] = mrow[mf * 16 + crow + r];
#pragma unroll
      for (int nf = 0; nf < 4; ++nf) {
        int d = nf * 16 + ccol;
#pragma unroll
        for (int r = 0; r < 4; ++r) {
          int key = mf * 16 + crow + r;
          tw[d * 128 + ((((key >> 3) ^ (d & 7)) << 3) | (key & 7))] =
              f2bf(mvv[r] ? acc[mf][nf][r] : 0.f);
        }
      }
    }
    u16* vb = Vt + ((size_t)(b * 16 + h) * 64) * NKP_;
    int key0 = seq0;                 // wave's 128 keys start at seq0
    int dr = lane >> 3, kc8 = (lane & 7);
#pragma unroll
    for (int j = 0; j < 8; ++j) {
      int d = j * 8 + dr;
#pragma unroll
      for (int half = 0; half < 2; ++half) {
        int kslot = kc8 + half * 8;  // key-group 0..15 (keys kslot*8..+7)
        bf16x8 vv = *(const bf16x8*)&tw[d * 128 + (((kslot ^ (d & 7)) & 15) * 8)];
        *(bf16x8*)(vb + (size_t)d * NKP_ + key0 + kslot * 8) = vv;
      }
    }
  }
}

// ===== 128^2-tile blocking GEMM body (m97 structure) for the out-proj =====
#define GEMM_BODY(A, Bt)                                                       \
  int tid = threadIdx.x, lane = tid & 63, wid = tid >> 6;                      \
  int m0 = blockIdx.x * 128, n0 = blockIdx.y * 128;                            \
  int wm = (wid >> 1) * 64, wn = (wid & 1) * 64;                               \
  int sr = lane >> 3;                                                          \
  int scz = ((lane & 7) ^ (lane >> 3)) * 8;                                    \
  int la = lane & 15, lk = (lane >> 4) * 8;                                    \
  int swz = (la & 7) * 8;                                                      \
  f32x4 acc[4][4] = {};                                                        \
  for (int kt = 0; kt < 16; ++kt) {                                            \
    int k0_ = kt * 64;                                                         \
    __syncthreads();                                                           \
    _Pragma("unroll")                                                          \
    for (int i_ = 0; i_ < 4; ++i_) {                                           \
      int r_ = i_ * 32 + wid * 8;                                              \
      load_lds16(A + (size_t)(m0 + r_ + sr) * 1024 + k0_ + scz, &a_sm[r_ * 64]); \
      load_lds16(Bt + (size_t)(n0 + r_ + sr) * 1024 + k0_ + scz, &b_sm[r_ * 64]); \
    }                                                                          \
    __syncthreads();                                                           \
    _Pragma("unroll")                                                          \
    for (int s = 0; s < 2; ++s) {                                              \
      bf16x8 af[4], bfr[4];                                                    \
      _Pragma("unroll")                                                        \
      for (int mf = 0; mf < 4; ++mf)                                           \
        af[mf] = *(const bf16x8*)&a_sm[(wm + mf * 16 + la) * 64 + ((s * 32 + lk) ^ swz)]; \
      _Pragma("unroll")                                                        \
      for (int nf = 0; nf < 4; ++nf)                                           \
        bfr[nf] = *(const bf16x8*)&b_sm[(wn + nf * 16 + la) * 64 + ((s * 32 + lk) ^ swz)]; \
      _Pragma("unroll")                                                        \
      for (int mf = 0; mf < 4; ++mf)                                           \
        _Pragma("unroll")                                                      \
        for (int nf = 0; nf < 4; ++nf)                                         \
          acc[mf][nf] = __builtin_amdgcn_mfma_f32_16x16x32_bf16(af[mf], bfr[nf], acc[mf][nf], 0, 0, 0); \
    }                                                                          \
  }                                                                            \
  int crow = (lane >> 4) * 4, ccol = lane & 15;

// ------------- out-proj GEMM: attn_out x woT -> f32 d_out -------------
__global__ __launch_bounds__(256) void gemm_out(const u16* __restrict__ A,
                                                const u16* __restrict__ Bt,
                                                float* __restrict__ C) {
  __shared__ __attribute__((aligned(16))) u16 sm[2 * 128 * 64];  // 32 KB
  u16* a_sm = sm;
  u16* b_sm = sm + 128 * 64;
  GEMM_BODY(A, Bt)
#pragma unroll
  for (int mf = 0; mf < 4; ++mf)
#pragma unroll
    for (int nf = 0; nf < 4; ++nf) {
      int rr = m0 + wm + mf * 16 + crow;
      int cc = n0 + wn + nf * 16 + ccol;
#pragma unroll
      for (int r = 0; r < 4; ++r) C[(size_t)(rr + r) * 1024 + cc] = acc[mf][nf][r];
    }
}

// ------------- flash attention -------------
// SINGLE-buffered K/V (was dbuf): LDS = k 8 + v 8 + p 32 = 48 KB -> 3
// blocks/CU (vs 2), 768 slots >= 512 blocks still one round, and THREE
// independent barrier groups per CU (+50% TLP) hide the now-exposed per-tile
// K/V load latency (m97/m114 mechanism: inter-block TLP does the pipelining).
// Blocking loop {sync; STAGE(kt); sync; compute} is strictly race-free.
// Everything else unchanged: swapped QK^T, maskless fixed-max exp2 softmax,
// b64 P-writes, XOR-swizzled LDS, pre-swizzled sources, T5 setprio.
__global__ __launch_bounds__(512) void attn_kernel(const u16* __restrict__ Q,
                                                   const u16* __restrict__ Kb,
                                                   const u16* __restrict__ Vt,
                                                   const float* __restrict__ cb,
                                                   u16* __restrict__ O) {
  __shared__ __attribute__((aligned(16))) u16 k_sm[64 * 64];     // [key][d], swizzled
  __shared__ __attribute__((aligned(16))) u16 v_sm[64 * 64];     // [d][key], swizzled
  __shared__ __attribute__((aligned(16))) u16 p_sm[8][32 * 64];  // per-wave P [q][key], swizzled
  int tid = threadIdx.x, lane = tid & 63, wid = tid >> 6;        // wid 0..7
  int bh = blockIdx.x, b = bh >> 4, h = bh & 15;
  int q0 = blockIdx.y * 256 + wid * 32;
  int la = lane & 15, lk = (lane >> 4) * 8, crow = (lane >> 4) * 4;
  int swz = (la & 7) * 8;                           // read-side XOR (row = x*16+la)
  int sr = lane >> 3;
  int scz = ((lane & 7) ^ (lane >> 3)) * 8;         // pre-swizzled source column

  bf16x8 aq[2][2];
#pragma unroll
  for (int qb = 0; qb < 2; ++qb) {
    const u16* qrow = Q + ((size_t)(b * N_) + q0 + qb * 16 + la) * D_ + h * DH_;
#pragma unroll
    for (int s = 0; s < 2; ++s) aq[qb][s] = *(const bf16x8*)(qrow + s * 32 + lk);
  }
  float l[2] = {0.f, 0.f};                          // per-lane partial sums (q = la)
  f32x4 o[2][4] = {};
  const u16* Kbh = Kb + (size_t)bh * NKP_ * 64;
  const u16* Vbh = Vt + (size_t)bh * 64 * NKP_;
  const float C1 = 11.541560327111707f;             // 8*log2(e)
  const float cbias = cb[0];                        // -8*max|qs*ks|*log2(e)
  const float lsub = cb[1 + b];                     // zero-key l mass to remove

  for (int kt = 0; kt < NKT_; ++kt) {
    int key0 = kt * 64;
    __syncthreads();  // WAR: all waves done reading previous tile
    {                 // each wave stages 8 K-rows + 8 V-rows
      int r_ = wid * 8;
      load_lds16(Kbh + (size_t)(key0 + r_ + sr) * 64 + scz, &k_sm[r_ * 64]);
      load_lds16(Vbh + (size_t)(r_ + sr) * NKP_ + key0 + scz, &v_sm[r_ * 64]);
    }
    __syncthreads();  // RAW: vmcnt(0) drain -> tile visible to all waves

    f32x4 sacc[2][4] = {};
    __builtin_amdgcn_s_setprio(1);
#pragma unroll
    for (int nf = 0; nf < 4; ++nf) {
      bf16x8 bk0 = *(const bf16x8*)&k_sm[(nf * 16 + la) * 64 + (lk ^ swz)];
      bf16x8 bk1 = *(const bf16x8*)&k_sm[(nf * 16 + la) * 64 + ((32 + lk) ^ swz)];
#pragma unroll
      for (int qb = 0; qb < 2; ++qb) {
        sacc[qb][nf] = __builtin_amdgcn_mfma_f32_16x16x32_bf16(bk0, aq[qb][0], sacc[qb][nf], 0, 0, 0);
        sacc[qb][nf] = __builtin_amdgcn_mfma_f32_16x16x32_bf16(bk1, aq[qb][1], sacc[qb][nf], 0, 0, 0);
      }
    }
    __builtin_amdgcn_s_setprio(0);

#pragma unroll
    for (int nf = 0; nf < 4; ++nf) {
      int key = nf * 16 + crow;
#pragma unroll
      for (int qb = 0; qb < 2; ++qb) {
        float p0 = __builtin_amdgcn_exp2f(fmaf(sacc[qb][nf][0], C1, cbias));
        float p1 = __builtin_amdgcn_exp2f(fmaf(sacc[qb][nf][1], C1, cbias));
        float p2 = __builtin_amdgcn_exp2f(fmaf(sacc[qb][nf][2], C1, cbias));
        float p3 = __builtin_amdgcn_exp2f(fmaf(sacc[qb][nf][3], C1, cbias));
        l[qb] += (p0 + p1) + (p2 + p3);
        uint2 pw;
        pw.x = cvtpk(p0, p1);
        pw.y = cvtpk(p2, p3);
        *(uint2*)&p_sm[wid][(qb * 16 + la) * 64 + (key ^ swz)] = pw;
      }
    }

    __builtin_amdgcn_s_setprio(1);
#pragma unroll
    for (int s = 0; s < 2; ++s) {
      bf16x8 bv[4];
#pragma unroll
      for (int dt = 0; dt < 4; ++dt)
        bv[dt] = *(const bf16x8*)&v_sm[(dt * 16 + la) * 64 + ((s * 32 + lk) ^ swz)];
#pragma unroll
      for (int qb = 0; qb < 2; ++qb) {
        bf16x8 ap = *(const bf16x8*)&p_sm[wid][(qb * 16 + la) * 64 + ((s * 32 + lk) ^ swz)];
#pragma unroll
        for (int dt = 0; dt < 4; ++dt)
          o[qb][dt] = __builtin_amdgcn_mfma_f32_16x16x32_bf16(ap, bv[dt], o[qb][dt], 0, 0, 0);
      }
    }
    __builtin_amdgcn_s_setprio(0);
  }

#pragma unroll
  for (int qb = 0; qb < 2; ++qb) {
    l[qb] += __shfl_xor(l[qb], 16, 64);
    l[qb] += __shfl_xor(l[qb], 32, 64);
#pragma unroll
    for (int r = 0; r < 4; ++r) {
      float lq = __shfl(l[qb], crow + r, 64) - lsub;  // remove zeroed-key mass
      float inv = 1.0f / lq;
      int n = q0 + qb * 16 + crow + r;
      u16* ob = O + ((size_t)(b * N_) + n) * D_ + h * DH_;
#pragma unroll
      for (int dt = 0; dt < 4; ++dt) ob[dt * 16 + la] = f2bf(o[qb][dt][r] * inv);
    }
  }
}

extern "C" void kernel_launch(void* const* d_in, const int* in_sizes, int n_in,
                              void* d_out, int out_size, void* d_ws, size_t ws_size,
                              hipStream_t stream) {
  (void)in_sizes; (void)n_in; (void)out_size; (void)ws_size;
  const float* x     = (const float*)d_in[0];
  const int*   mask  = (const int*)d_in[1];
  const float* gamma = (const float*)d_in[2];
  const float* wq    = (const float*)d_in[3];
  const float* wkv   = (const float*)d_in[4];
  const float* nkv   = (const float*)d_in[5];
  const float* qs    = (const float*)d_in[6];
  const float* ksc   = (const float*)d_in[7];
  const float* wo    = (const float*)d_in[8];

  // workspace layout (~59 MiB)
  char* ws   = (char*)d_ws;
  u16* xn    = (u16*)(ws);                        // 16 MiB; reused as attn_out
  u16* wqkvT = (u16*)(ws + (16ull << 20));        // 6 MiB: wqT[1024] + wkvT[2048] rows
  u16* woT   = (u16*)(ws + (22ull << 20));        // 2 MiB
  u16* Kb    = (u16*)(ws + (24ull << 20));        // 16.5 MiB
  u16* Vt    = (u16*)(ws + (41ull << 20));        // 16.5 MiB
  float* cb  = (float*)(ws + (58ull << 20));      // 5 floats
  u16* q_tmp = (u16*)d_out;                       // 16 MiB scratch inside 32 MiB d_out
  u16* attn_out = xn;                             // alias: xn dead after qkv GEMM

  ln_kernel<<<B_ * N_, 256, 0, stream>>>(x, gamma, xn);
  wt3_kernel<<<4096, 256, 0, stream>>>(wq, wkv, wo, wqkvT, woT);
  prep_kernel<<<64, 256, 0, stream>>>(mask, qs, ksc, nkv, Kb, Vt, cb);
  gemm_qkv<<<dim3(32, 12), 512, 0, stream>>>(xn, wqkvT, q_tmp, Kb, Vt, qs, ksc, mask);
  attn_kernel<<<dim3(64, 8), 512, 0, stream>>>(q_tmp, Kb, Vt, cb, attn_out);
  gemm_out<<<dim3(64, 8), 256, 0, stream>>>(attn_out, woT, (float*)d_out);
}

// Round 21
// 200.273 us; speedup vs baseline: 1.0070x; 1.0070x over previous
//
#include <hip/hip_runtime.h>

typedef unsigned short u16;
typedef unsigned int u32;
typedef unsigned long long u64;
typedef __bf16 bf16x8 __attribute__((ext_vector_type(8)));
typedef float f32x4 __attribute__((ext_vector_type(4)));

#define B_ 4
#define N_ 2048
#define D_ 1024
#define H_ 16
#define DH_ 64
#define NKP_ 2112   // padded key slots: 33*64.  slots 0..2047 = seq keys,
#define NKT_ 33     // slot 2048 = null kv (always visible), 2049+ = zero pad

__device__ __forceinline__ float bf2f(u16 u) {
  union { u32 i; float f; } v; v.i = ((u32)u) << 16; return v.f;
}
__device__ __forceinline__ u16 f2bf(float f) {
  union { float f; u32 i; } v; v.f = f;
  u32 r = v.i + 0x7fffu + ((v.i >> 16) & 1u);
  return (u16)(r >> 16);
}
__device__ __forceinline__ u32 cvtpk(float a, float b) {  // {lo=bf16(a), hi=bf16(b)}
  u32 r;
  asm("v_cvt_pk_bf16_f32 %0, %1, %2" : "=v"(r) : "v"(a), "v"(b));
  return r;
}
__device__ __forceinline__ void load_lds16(const void* g, void* l) {
  __builtin_amdgcn_global_load_lds((const __attribute__((address_space(1))) void*)g,
                                   (__attribute__((address_space(3))) void*)l, 16, 0, 0);
}

// ---------------- LayerNorm: x f32 [8192][1024] -> xn bf16 ----------------
__global__ __launch_bounds__(256) void ln_kernel(const float* __restrict__ x,
                                                 const float* __restrict__ gamma,
                                                 u16* __restrict__ xn) {
  int row = blockIdx.x;
  int tid = threadIdx.x, lane = tid & 63, wid = tid >> 6;
  const float4 v = ((const float4*)(x + (size_t)row * D_))[tid];
  float s  = v.x + v.y + v.z + v.w;
  float ss = v.x * v.x + v.y * v.y + v.z * v.z + v.w * v.w;
#pragma unroll
  for (int off = 1; off < 64; off <<= 1) {
    s  += __shfl_xor(s,  off, 64);
    ss += __shfl_xor(ss, off, 64);
  }
  __shared__ float rs[4], rss[4];
  if (lane == 0) { rs[wid] = s; rss[wid] = ss; }
  __syncthreads();
  float S  = rs[0] + rs[1] + rs[2] + rs[3];
  float SS = rss[0] + rss[1] + rss[2] + rss[3];
  float mean = S * (1.0f / D_);
  float var  = SS * (1.0f / D_) - mean * mean;
  float inv  = rsqrtf(var + 1e-5f);
  const float4 g = ((const float4*)gamma)[tid];
  ushort4 o;
  o.x = f2bf((v.x - mean) * inv * g.x);
  o.y = f2bf((v.y - mean) * inv * g.y);
  o.z = f2bf((v.z - mean) * inv * g.z);
  o.w = f2bf((v.w - mean) * inv * g.w);
  *(ushort4*)(xn + (size_t)row * D_ + tid * 4) = o;
}

// ------- merged weight transpose+cast: {wq, wkv, wo} in ONE launch -------
__global__ __launch_bounds__(256) void wt3_kernel(const float* __restrict__ wq,
                                                  const float* __restrict__ wkv,
                                                  const float* __restrict__ wo,
                                                  u16* __restrict__ wqkvT,
                                                  u16* __restrict__ woT) {
  int t = blockIdx.x;
  const float* W;
  u16* WT;
  int N, tile;
  if (t < 1024)      { W = wq;  WT = wqkvT;                N = 1024; tile = t; }
  else if (t < 3072) { W = wkv; WT = wqkvT + 1024 * 1024;  N = 2048; tile = t - 1024; }
  else               { W = wo;  WT = woT;                  N = 1024; tile = t - 3072; }
  __shared__ float tb[32][33];
  int tiles_n = N >> 5;
  int tk = tile / tiles_n, tn = tile % tiles_n;
  int tx = threadIdx.x & 31, ty = threadIdx.x >> 5;  // ty in [0,8)
  int k0 = tk << 5, n0 = tn << 5;
#pragma unroll
  for (int i = 0; i < 4; ++i)
    tb[ty + i * 8][tx] = W[(size_t)(k0 + ty + i * 8) * N + n0 + tx];
  __syncthreads();
#pragma unroll
  for (int i = 0; i < 4; ++i)
    WT[(size_t)(n0 + ty + i * 8) * 1024 + k0 + tx] = f2bf(tb[tx][ty + i * 8]);
}

// ------------- prep: null KV row, zero pads, masked-key counts, softmax shift ----
__global__ __launch_bounds__(256) void prep_kernel(const int* __restrict__ mask,
                                                   const float* __restrict__ qs,
                                                   const float* __restrict__ ksc,
                                                   const float* __restrict__ null_kv,
                                                   u16* __restrict__ Kb,
                                                   u16* __restrict__ Vt,
                                                   float* __restrict__ cb) {
  __shared__ int cnts[4];
  int bh = blockIdx.x, h = bh & 15;
  int tid = threadIdx.x, lane = tid & 63, wid = tid >> 6;
  if (wid == 0) {
    float kv = null_kv[h * 64 + lane];
    float ss = kv * kv;
#pragma unroll
    for (int off = 1; off < 64; off <<= 1) ss += __shfl_xor(ss, off, 64);
    float inv = 1.0f / fmaxf(sqrtf(ss), 1e-12f);
    Kb[((size_t)bh * NKP_ + 2048) * 64 + lane] = f2bf(kv * inv * ksc[lane]);
    Vt[((size_t)bh * 64 + lane) * NKP_ + 2048] = f2bf(null_kv[1024 + h * 64 + lane]);
  }
  for (int i = tid; i < 63 * 64; i += 256) {  // Kb pad rows 2049..2111
    int r = i >> 6, c = i & 63;
    Kb[((size_t)bh * NKP_ + 2049 + r) * 64 + c] = 0;
  }
  for (int i = tid; i < 64 * 63; i += 256) {  // Vt pad cols 2049..2111
    int d = i / 63, c = i % 63;
    Vt[((size_t)bh * 64 + d) * NKP_ + 2049 + c] = 0;
  }
  if (bh == 0) {
    if (tid < 4) cnts[tid] = 0;
    __syncthreads();
    int c0 = 0, c1 = 0, c2 = 0, c3 = 0;
    for (int i = tid; i < B_ * N_; i += 256) {
      int z = (mask[i] == 0);
      int b = i >> 11;
      if (b == 0) c0 += z; else if (b == 1) c1 += z; else if (b == 2) c2 += z; else c3 += z;
    }
    atomicAdd(&cnts[0], c0); atomicAdd(&cnts[1], c1);
    atomicAdd(&cnts[2], c2); atomicAdd(&cnts[3], c3);
    __syncthreads();
    if (tid == 0) {
      float mw = 0.f;
      for (int i = 0; i < DH_; ++i) mw = fmaxf(mw, fabsf(qs[i] * ksc[i]));
      float cbias = -8.0f * mw * 1.4426950408889634f;
      cb[0] = cbias;
      float e = __builtin_amdgcn_exp2f(cbias);  // same HW instr as attn's exp2
#pragma unroll
      for (int b = 0; b < 4; ++b) cb[1 + b] = (float)(cnts[b] + 63) * e;
    }
  }
}

// ------------- fused QKV GEMM, 256x256 tile, 8 waves, dbuf 128 KB LDS -------------
// MEASURED-BEST (R10/R16/R18: ~104.5 us, total 200.3).  Design space closed:
// blocking 1-tile 104.8 / counted 1-deep 108 / counted 3-deep 108-111 /
// 2blk-TLP 108.9 / blocking 2-tile 114.5.  Binder = staging drain; escape
// needs the full m201 8-phase interleave (out of headless risk budget).
__global__ __launch_bounds__(512, 1) void gemm_qkv(const u16* __restrict__ A,
                                                   const u16* __restrict__ Bt,
                                                   u16* __restrict__ Qo,
                                                   u16* __restrict__ Kb,
                                                   u16* __restrict__ Vt,
                                                   const float* __restrict__ qs,
                                                   const float* __restrict__ ksc,
                                                   const int* __restrict__ Mask) {
  __shared__ __attribute__((aligned(16))) u16 dsm[65536];  // 128 KB: [buf][A|B][256*64]
  int bx = blockIdx.x, by = blockIdx.y;
  int tid = threadIdx.x, lane = tid & 63, wid = tid >> 6;  // wid 0..7
  int wr = wid >> 2, wc = wid & 3;
  int m0 = bx * 256, n0 = by * 256;
  int wm = wr * 128, wn = wc * 64;
  int la = lane & 15, hi = lane >> 4, crow = hi * 4;
  int sr = lane >> 3;
  int scz = ((lane & 7) ^ (lane >> 3)) * 8;  // pre-swizzled source column (elems)
  f32x4 acc[8][4] = {};

#define QSTAGE(buf, kt)                                                        \
  do {                                                                         \
    int k0_ = (kt) * 64;                                                       \
    u16* ab_ = dsm + (buf) * 32768;                                            \
    _Pragma("unroll")                                                          \
    for (int r4 = 0; r4 < 4; ++r4) {                                           \
      int r_ = r4 * 64 + wid * 8;       /* wave-uniform row base */            \
      load_lds16(A  + (size_t)(m0 + r_ + sr) * 1024 + k0_ + scz, ab_ + r_ * 64); \
      load_lds16(Bt + (size_t)(n0 + r_ + sr) * 1024 + k0_ + scz, ab_ + 16384 + r_ * 64); \
    }                                                                          \
  } while (0)

  QSTAGE(0, 0);

  for (int kt = 0; kt < 16; ++kt) {
    int buf = kt & 1;
    __syncthreads();  // drains vmcnt: tile kt present; tile kt-1 fully consumed
    if (kt + 1 < 16) QSTAGE(buf ^ 1, kt + 1);
    const u16* a_l = dsm + buf * 32768;
    const u16* b_l = a_l + 16384;
    __builtin_amdgcn_s_setprio(1);
#pragma unroll
    for (int s = 0; s < 2; ++s) {
      int slotbase = s * 4 + hi;  // k-group; LDS slot = group ^ (row&7), row&7 = la&7
      bf16x8 bfr[4];
#pragma unroll
      for (int nf = 0; nf < 4; ++nf)
        bfr[nf] = *(const bf16x8*)&b_l[(wn + nf * 16 + la) * 64 + ((slotbase ^ (la & 7)) * 8)];
#pragma unroll
      for (int mf = 0; mf < 8; ++mf) {
        bf16x8 af = *(const bf16x8*)&a_l[(wm + mf * 16 + la) * 64 + ((slotbase ^ (la & 7)) * 8)];
#pragma unroll
        for (int nf = 0; nf < 4; ++nf)
          acc[mf][nf] = __builtin_amdgcn_mfma_f32_16x16x32_bf16(af, bfr[nf], acc[mf][nf], 0, 0, 0);
      }
    }
    __builtin_amdgcn_s_setprio(0);
  }
#undef QSTAGE

  int ccol = la;
  if (by < 4) {
    // ---- q: fused per-head l2norm * qs (wave cols = one head) ----
    float qsv[4];
#pragma unroll
    for (int nf = 0; nf < 4; ++nf) qsv[nf] = qs[nf * 16 + ccol];
#pragma unroll
    for (int mf = 0; mf < 8; ++mf) {
      float invr[4];
#pragma unroll
      for (int r = 0; r < 4; ++r) {
        float ss = 0.f;
#pragma unroll
        for (int nf = 0; nf < 4; ++nf) ss += acc[mf][nf][r] * acc[mf][nf][r];
#pragma unroll
        for (int off = 1; off < 16; off <<= 1) ss += __shfl_xor(ss, off, 64);
        invr[r] = 1.0f / fmaxf(sqrtf(ss), 1e-12f);
      }
#pragma unroll
      for (int nf = 0; nf < 4; ++nf) {
        int rr = m0 + wm + mf * 16 + crow;
        int cc = by * 256 + wn + nf * 16 + ccol;
#pragma unroll
        for (int r = 0; r < 4; ++r)
          Qo[(size_t)(rr + r) * 1024 + cc] = f2bf(acc[mf][nf][r] * invr[r] * qsv[nf]);
      }
    }
    return;
  }

  int rr0 = m0 + wm;          // wave's 128 rows; never crosses batch boundary
  int b = rr0 >> 11;
  int seq0 = rr0 & 2047;
  const int* mrow = Mask + b * N_ + seq0;
  if (by < 8) {
    // ---- K: fused l2norm * ksc, masked rows zeroed -> Kb[bh][key][64] ----
    int h = (by - 4) * 4 + wc;
    float kscv[4];
#pragma unroll
    for (int nf = 0; nf < 4; ++nf) kscv[nf] = ksc[nf * 16 + ccol];
    u16* kb = Kb + ((size_t)(b * 16 + h) * NKP_) * 64;
#pragma unroll
    for (int mf = 0; mf < 8; ++mf) {
      float invr[4]; int mvv[4];
#pragma unroll
      for (int r = 0; r < 4; ++r) {
        float ss = 0.f;
#pragma unroll
        for (int nf = 0; nf < 4; ++nf) ss += acc[mf][nf][r] * acc[mf][nf][r];
#pragma unroll
        for (int off = 1; off < 16; off <<= 1) ss += __shfl_xor(ss, off, 64);
        invr[r] = 1.0f / fmaxf(sqrtf(ss), 1e-12f);
        mvv[r] = mrow[mf * 16 + crow + r];  // row-uniform -> broadcast load
      }
#pragma unroll
      for (int nf = 0; nf < 4; ++nf)
#pragma unroll
        for (int r = 0; r < 4; ++r)
          kb[(size_t)(seq0 + mf * 16 + crow + r) * 64 + nf * 16 + ccol] =
              f2bf(mvv[r] ? acc[mf][nf][r] * invr[r] * kscv[nf] : 0.f);
    }
  } else {
    // ---- V: mask-zero, transpose 128key x 64d wave tile via LDS -> Vt ----
    int h = (by - 8) * 4 + wc;
    __syncthreads();                 // all waves done reading gemm tiles
    u16* tw = dsm + wid * 8192;      // per-wave [64 d][128 key], key-slot swizzled
#pragma unroll
    for (int mf = 0; mf < 8; ++mf) {
      int mvv[4];
#pragma unroll
      for (int r = 0; r < 4; ++r) mvv[r] = mrow[mf * 16 + crow + r];
#pragma unroll
      for (int nf = 0; nf < 4; ++nf) {
        int d = nf * 16 + ccol;
#pragma unroll
        for (int r = 0; r < 4; ++r) {
          int key = mf * 16 + crow + r;
          tw[d * 128 + ((((key >> 3) ^ (d & 7)) << 3) | (key & 7))] =
              f2bf(mvv[r] ? acc[mf][nf][r] : 0.f);
        }
      }
    }
    u16* vb = Vt + ((size_t)(b * 16 + h) * 64) * NKP_;
    int key0 = seq0;                 // wave's 128 keys start at seq0
    int dr = lane >> 3, kc8 = (lane & 7);
#pragma unroll
    for (int j = 0; j < 8; ++j) {
      int d = j * 8 + dr;
#pragma unroll
      for (int half = 0; half < 2; ++half) {
        int kslot = kc8 + half * 8;  // key-group 0..15 (keys kslot*8..+7)
        bf16x8 vv = *(const bf16x8*)&tw[d * 128 + (((kslot ^ (d & 7)) & 15) * 8)];
        *(bf16x8*)(vb + (size_t)d * NKP_ + key0 + kslot * 8) = vv;
      }
    }
  }
}

// ===== 128^2-tile blocking GEMM body (m97 structure) for the out-proj =====
#define GEMM_BODY(A, Bt)                                                       \
  int tid = threadIdx.x, lane = tid & 63, wid = tid >> 6;                      \
  int m0 = blockIdx.x * 128, n0 = blockIdx.y * 128;                            \
  int wm = (wid >> 1) * 64, wn = (wid & 1) * 64;                               \
  int sr = lane >> 3;                                                          \
  int scz = ((lane & 7) ^ (lane >> 3)) * 8;                                    \
  int la = lane & 15, lk = (lane >> 4) * 8;                                    \
  int swz = (la & 7) * 8;                                                      \
  f32x4 acc[4][4] = {};                                                        \
  for (int kt = 0; kt < 16; ++kt) {                                            \
    int k0_ = kt * 64;                                                         \
    __syncthreads();                                                           \
    _Pragma("unroll")                                                          \
    for (int i_ = 0; i_ < 4; ++i_) {                                           \
      int r_ = i_ * 32 + wid * 8;                                              \
      load_lds16(A + (size_t)(m0 + r_ + sr) * 1024 + k0_ + scz, &a_sm[r_ * 64]); \
      load_lds16(Bt + (size_t)(n0 + r_ + sr) * 1024 + k0_ + scz, &b_sm[r_ * 64]); \
    }                                                                          \
    __syncthreads();                                                           \
    _Pragma("unroll")                                                          \
    for (int s = 0; s < 2; ++s) {                                              \
      bf16x8 af[4], bfr[4];                                                    \
      _Pragma("unroll")                                                        \
      for (int mf = 0; mf < 4; ++mf)                                           \
        af[mf] = *(const bf16x8*)&a_sm[(wm + mf * 16 + la) * 64 + ((s * 32 + lk) ^ swz)]; \
      _Pragma("unroll")                                                        \
      for (int nf = 0; nf < 4; ++nf)                                           \
        bfr[nf] = *(const bf16x8*)&b_sm[(wn + nf * 16 + la) * 64 + ((s * 32 + lk) ^ swz)]; \
      _Pragma("unroll")                                                        \
      for (int mf = 0; mf < 4; ++mf)                                           \
        _Pragma("unroll")                                                      \
        for (int nf = 0; nf < 4; ++nf)                                         \
          acc[mf][nf] = __builtin_amdgcn_mfma_f32_16x16x32_bf16(af[mf], bfr[nf], acc[mf][nf], 0, 0, 0); \
    }                                                                          \
  }                                                                            \
  int crow = (lane >> 4) * 4, ccol = lane & 15;

// ------------- out-proj GEMM: attn_out x woT -> f32 d_out -------------
__global__ __launch_bounds__(256) void gemm_out(const u16* __restrict__ A,
                                                const u16* __restrict__ Bt,
                                                float* __restrict__ C) {
  __shared__ __attribute__((aligned(16))) u16 sm[2 * 128 * 64];  // 32 KB
  u16* a_sm = sm;
  u16* b_sm = sm + 128 * 64;
  GEMM_BODY(A, Bt)
#pragma unroll
  for (int mf = 0; mf < 4; ++mf)
#pragma unroll
    for (int nf = 0; nf < 4; ++nf) {
      int rr = m0 + wm + mf * 16 + crow;
      int cc = n0 + wn + nf * 16 + ccol;
#pragma unroll
      for (int r = 0; r < 4; ++r) C[(size_t)(rr + r) * 1024 + cc] = acc[mf][nf][r];
    }
}

// ------------- flash attention (measured best: ~90 us, dbuf K/V) -------------
// grid (bh=64, qtile=8), 8 waves/block (512 thr), 32 q-rows/wave, 64-key tiles.
// LDS 64 KB -> 2 blocks/CU -> 512 slots = grid: single full round.  Swapped
// QK^T; MASKLESS fixed-max softmax in exp2 domain (masked keys K=0,V=0; mass
// cb[1+b] subtracted in epilogue).  b64 P-writes; XOR-swizzled LDS; 2-phase
// dbuf; T5 setprio; kt loop unrolled x2.  R19 A/B: 3-blocks/CU single-buffer
// variant was null -> attn is intra-wave dependency-chain-bound; dbuf kept.
__global__ __launch_bounds__(512) void attn_kernel(const u16* __restrict__ Q,
                                                   const u16* __restrict__ Kb,
                                                   const u16* __restrict__ Vt,
                                                   const float* __restrict__ cb,
                                                   u16* __restrict__ O) {
  __shared__ __attribute__((aligned(16))) u16 k_sm[2][64 * 64];  // [key][d], swizzled
  __shared__ __attribute__((aligned(16))) u16 v_sm[2][64 * 64];  // [d][key], swizzled
  __shared__ __attribute__((aligned(16))) u16 p_sm[8][32 * 64];  // per-wave P [q][key], swizzled
  int tid = threadIdx.x, lane = tid & 63, wid = tid >> 6;        // wid 0..7
  int bh = blockIdx.x, b = bh >> 4, h = bh & 15;
  int q0 = blockIdx.y * 256 + wid * 32;
  int la = lane & 15, lk = (lane >> 4) * 8, crow = (lane >> 4) * 4;
  int swz = (la & 7) * 8;                           // read-side XOR (row = x*16+la)
  int sr = lane >> 3;
  int scz = ((lane & 7) ^ (lane >> 3)) * 8;         // pre-swizzled source column

  bf16x8 aq[2][2];
#pragma unroll
  for (int qb = 0; qb < 2; ++qb) {
    const u16* qrow = Q + ((size_t)(b * N_) + q0 + qb * 16 + la) * D_ + h * DH_;
#pragma unroll
    for (int s = 0; s < 2; ++s) aq[qb][s] = *(const bf16x8*)(qrow + s * 32 + lk);
  }
  float l[2] = {0.f, 0.f};                          // per-lane partial sums (q = la)
  f32x4 o[2][4] = {};
  const u16* Kbh = Kb + (size_t)bh * NKP_ * 64;
  const u16* Vbh = Vt + (size_t)bh * 64 * NKP_;
  const float C1 = 11.541560327111707f;             // 8*log2(e)
  const float cbias = cb[0];                        // -8*max|qs*ks|*log2(e)
  const float lsub = cb[1 + b];                     // zero-key l mass to remove

#define STAGE(bb, kt)                                                          \
  do {                                                                         \
    int key0_ = (kt) * 64;                                                     \
    int r_ = wid * 8;                                                          \
    load_lds16(Kbh + (size_t)(key0_ + r_ + sr) * 64 + scz, &k_sm[bb][r_ * 64]); \
    load_lds16(Vbh + (size_t)(r_ + sr) * NKP_ + key0_ + scz, &v_sm[bb][r_ * 64]); \
  } while (0)

  STAGE(0, 0);

#pragma unroll 2
  for (int kt = 0; kt < NKT_; ++kt) {
    int bb = kt & 1;
    __syncthreads();  // drains vmcnt: STAGE(kt) complete; prev-tile reads done
    if (kt + 1 < NKT_) STAGE(bb ^ 1, kt + 1);

    f32x4 sacc[2][4] = {};
    __builtin_amdgcn_s_setprio(1);
#pragma unroll
    for (int nf = 0; nf < 4; ++nf) {
      bf16x8 bk0 = *(const bf16x8*)&k_sm[bb][(nf * 16 + la) * 64 + (lk ^ swz)];
      bf16x8 bk1 = *(const bf16x8*)&k_sm[bb][(nf * 16 + la) * 64 + ((32 + lk) ^ swz)];
#pragma unroll
      for (int qb = 0; qb < 2; ++qb) {
        sacc[qb][nf] = __builtin_amdgcn_mfma_f32_16x16x32_bf16(bk0, aq[qb][0], sacc[qb][nf], 0, 0, 0);
        sacc[qb][nf] = __builtin_amdgcn_mfma_f32_16x16x32_bf16(bk1, aq[qb][1], sacc[qb][nf], 0, 0, 0);
      }
    }
    __builtin_amdgcn_s_setprio(0);

#pragma unroll
    for (int nf = 0; nf < 4; ++nf) {
      int key = nf * 16 + crow;
#pragma unroll
      for (int qb = 0; qb < 2; ++qb) {
        float p0 = __builtin_amdgcn_exp2f(fmaf(sacc[qb][nf][0], C1, cbias));
        float p1 = __builtin_amdgcn_exp2f(fmaf(sacc[qb][nf][1], C1, cbias));
        float p2 = __builtin_amdgcn_exp2f(fmaf(sacc[qb][nf][2], C1, cbias));
        float p3 = __builtin_amdgcn_exp2f(fmaf(sacc[qb][nf][3], C1, cbias));
        l[qb] += (p0 + p1) + (p2 + p3);
        uint2 pw;
        pw.x = cvtpk(p0, p1);
        pw.y = cvtpk(p2, p3);
        *(uint2*)&p_sm[wid][(qb * 16 + la) * 64 + (key ^ swz)] = pw;
      }
    }

    __builtin_amdgcn_s_setprio(1);
#pragma unroll
    for (int s = 0; s < 2; ++s) {
      bf16x8 bv[4];
#pragma unroll
      for (int dt = 0; dt < 4; ++dt)
        bv[dt] = *(const bf16x8*)&v_sm[bb][(dt * 16 + la) * 64 + ((s * 32 + lk) ^ swz)];
#pragma unroll
      for (int qb = 0; qb < 2; ++qb) {
        bf16x8 ap = *(const bf16x8*)&p_sm[wid][(qb * 16 + la) * 64 + ((s * 32 + lk) ^ swz)];
#pragma unroll
        for (int dt = 0; dt < 4; ++dt)
          o[qb][dt] = __builtin_amdgcn_mfma_f32_16x16x32_bf16(ap, bv[dt], o[qb][dt], 0, 0, 0);
      }
    }
    __builtin_amdgcn_s_setprio(0);
  }
#undef STAGE

#pragma unroll
  for (int qb = 0; qb < 2; ++qb) {
    l[qb] += __shfl_xor(l[qb], 16, 64);
    l[qb] += __shfl_xor(l[qb], 32, 64);
#pragma unroll
    for (int r = 0; r < 4; ++r) {
      float lq = __shfl(l[qb], crow + r, 64) - lsub;  // remove zeroed-key mass
      float inv = 1.0f / lq;
      int n = q0 + qb * 16 + crow + r;
      u16* ob = O + ((size_t)(b * N_) + n) * D_ + h * DH_;
#pragma unroll
      for (int dt = 0; dt < 4; ++dt) ob[dt * 16 + la] = f2bf(o[qb][dt][r] * inv);
    }
  }
}

extern "C" void kernel_launch(void* const* d_in, const int* in_sizes, int n_in,
                              void* d_out, int out_size, void* d_ws, size_t ws_size,
                              hipStream_t stream) {
  (void)in_sizes; (void)n_in; (void)out_size; (void)ws_size;
  const float* x     = (const float*)d_in[0];
  const int*   mask  = (const int*)d_in[1];
  const float* gamma = (const float*)d_in[2];
  const float* wq    = (const float*)d_in[3];
  const float* wkv   = (const float*)d_in[4];
  const float* nkv   = (const float*)d_in[5];
  const float* qs    = (const float*)d_in[6];
  const float* ksc   = (const float*)d_in[7];
  const float* wo    = (const float*)d_in[8];

  // workspace layout (~59 MiB)
  char* ws   = (char*)d_ws;
  u16* xn    = (u16*)(ws);                        // 16 MiB; reused as attn_out
  u16* wqkvT = (u16*)(ws + (16ull << 20));        // 6 MiB: wqT[1024] + wkvT[2048] rows
  u16* woT   = (u16*)(ws + (22ull << 20));        // 2 MiB
  u16* Kb    = (u16*)(ws + (24ull << 20));        // 16.5 MiB
  u16* Vt    = (u16*)(ws + (41ull << 20));        // 16.5 MiB
  float* cb  = (float*)(ws + (58ull << 20));      // 5 floats
  u16* q_tmp = (u16*)d_out;                       // 16 MiB scratch inside 32 MiB d_out
  u16* attn_out = xn;                             // alias: xn dead after qkv GEMM

  ln_kernel<<<B_ * N_, 256, 0, stream>>>(x, gamma, xn);
  wt3_kernel<<<4096, 256, 0, stream>>>(wq, wkv, wo, wqkvT, woT);
  prep_kernel<<<64, 256, 0, stream>>>(mask, qs, ksc, nkv, Kb, Vt, cb);
  gemm_qkv<<<dim3(32, 12), 512, 0, stream>>>(xn, wqkvT, q_tmp, Kb, Vt, qs, ksc, mask);
  attn_kernel<<<dim3(64, 8), 512, 0, stream>>>(q_tmp, Kb, Vt, cb, attn_out);
  gemm_out<<<dim3(64, 8), 256, 0, stream>>>(attn_out, woT, (float*)d_out);
}

// Round 22
// 195.312 us; speedup vs baseline: 1.0326x; 1.0254x over previous
//
#include <hip/hip_runtime.h>

typedef unsigned short u16;
typedef unsigned int u32;
typedef unsigned long long u64;
typedef __bf16 bf16x8 __attribute__((ext_vector_type(8)));
typedef float f32x4 __attribute__((ext_vector_type(4)));

#define B_ 4
#define N_ 2048
#define D_ 1024
#define H_ 16
#define DH_ 64
#define NKP_ 2112   // padded key slots: 33*64.  slots 0..2047 = seq keys,
#define NKT_ 33     // slot 2048 = null kv (always visible), 2049+ = zero pad

__device__ __forceinline__ float bf2f(u16 u) {
  union { u32 i; float f; } v; v.i = ((u32)u) << 16; return v.f;
}
__device__ __forceinline__ u16 f2bf(float f) {
  union { float f; u32 i; } v; v.f = f;
  u32 r = v.i + 0x7fffu + ((v.i >> 16) & 1u);
  return (u16)(r >> 16);
}
__device__ __forceinline__ u32 cvtpk(float a, float b) {  // {lo=bf16(a), hi=bf16(b)}
  u32 r;
  asm("v_cvt_pk_bf16_f32 %0, %1, %2" : "=v"(r) : "v"(a), "v"(b));
  return r;
}
__device__ __forceinline__ void load_lds16(const void* g, void* l) {
  __builtin_amdgcn_global_load_lds((const __attribute__((address_space(1))) void*)g,
                                   (__attribute__((address_space(3))) void*)l, 16, 0, 0);
}

// ------------- fused pre-pass: ln + weight-transpose + prep in ONE launch -------------
// blocks [0,8192): LayerNorm rows; [8192,12288): wt tiles (wq/wkv/wo);
// [12288,12352): prep (null-KV row, pads, mask counts, softmax shift).
// All three are mutually independent; fusing saves 2 kernel-boundary gaps and
// fills prep's 64-block tail under wt3's trailing blocks.
__global__ __launch_bounds__(256) void pre_kernel(const float* __restrict__ x,
                                                  const float* __restrict__ gamma,
                                                  u16* __restrict__ xn,
                                                  const float* __restrict__ wq,
                                                  const float* __restrict__ wkv,
                                                  const float* __restrict__ wo,
                                                  u16* __restrict__ wqkvT,
                                                  u16* __restrict__ woT,
                                                  const int* __restrict__ mask,
                                                  const float* __restrict__ qs,
                                                  const float* __restrict__ ksc,
                                                  const float* __restrict__ null_kv,
                                                  u16* __restrict__ Kb,
                                                  u16* __restrict__ Vt,
                                                  float* __restrict__ cb) {
  __shared__ float shf[32][33];  // 4224 B union: wt tile / ln partials / prep cnts
  int blk = blockIdx.x;
  int tid = threadIdx.x, lane = tid & 63, wid = tid >> 6;

  if (blk < 8192) {
    // ---------------- LayerNorm: x f32 [8192][1024] -> xn bf16 ----------------
    int row = blk;
    const float4 v = ((const float4*)(x + (size_t)row * D_))[tid];
    float s  = v.x + v.y + v.z + v.w;
    float ss = v.x * v.x + v.y * v.y + v.z * v.z + v.w * v.w;
#pragma unroll
    for (int off = 1; off < 64; off <<= 1) {
      s  += __shfl_xor(s,  off, 64);
      ss += __shfl_xor(ss, off, 64);
    }
    float* rs  = &shf[0][0];
    float* rss = &shf[0][8];
    if (lane == 0) { rs[wid] = s; rss[wid] = ss; }
    __syncthreads();
    float S  = rs[0] + rs[1] + rs[2] + rs[3];
    float SS = rss[0] + rss[1] + rss[2] + rss[3];
    float mean = S * (1.0f / D_);
    float var  = SS * (1.0f / D_) - mean * mean;
    float inv  = rsqrtf(var + 1e-5f);
    const float4 g = ((const float4*)gamma)[tid];
    ushort4 o;
    o.x = f2bf((v.x - mean) * inv * g.x);
    o.y = f2bf((v.y - mean) * inv * g.y);
    o.z = f2bf((v.z - mean) * inv * g.z);
    o.w = f2bf((v.w - mean) * inv * g.w);
    *(ushort4*)(xn + (size_t)row * D_ + tid * 4) = o;
    return;
  }

  if (blk < 12288) {
    // ------- weight transpose+cast: W f32 [K][N] -> WT bf16 [N][1024] -------
    int t = blk - 8192;
    const float* W;
    u16* WT;
    int N, tile;
    if (t < 1024)      { W = wq;  WT = wqkvT;                N = 1024; tile = t; }
    else if (t < 3072) { W = wkv; WT = wqkvT + 1024 * 1024;  N = 2048; tile = t - 1024; }
    else               { W = wo;  WT = woT;                  N = 1024; tile = t - 3072; }
    int tiles_n = N >> 5;
    int tk = tile / tiles_n, tn = tile % tiles_n;
    int tx = tid & 31, ty = tid >> 5;  // ty in [0,8)
    int k0 = tk << 5, n0 = tn << 5;
#pragma unroll
    for (int i = 0; i < 4; ++i)
      shf[ty + i * 8][tx] = W[(size_t)(k0 + ty + i * 8) * N + n0 + tx];
    __syncthreads();
#pragma unroll
    for (int i = 0; i < 4; ++i)
      WT[(size_t)(n0 + ty + i * 8) * 1024 + k0 + tx] = f2bf(shf[tx][ty + i * 8]);
    return;
  }

  // ------------- prep: null KV row, zero pads, masked-key counts, shift -------------
  int bh = blk - 12288, h = bh & 15;
  if (wid == 0) {
    float kv = null_kv[h * 64 + lane];
    float ss = kv * kv;
#pragma unroll
    for (int off = 1; off < 64; off <<= 1) ss += __shfl_xor(ss, off, 64);
    float inv = 1.0f / fmaxf(sqrtf(ss), 1e-12f);
    Kb[((size_t)bh * NKP_ + 2048) * 64 + lane] = f2bf(kv * inv * ksc[lane]);
    Vt[((size_t)bh * 64 + lane) * NKP_ + 2048] = f2bf(null_kv[1024 + h * 64 + lane]);
  }
  for (int i = tid; i < 63 * 64; i += 256) {  // Kb pad rows 2049..2111
    int r = i >> 6, c = i & 63;
    Kb[((size_t)bh * NKP_ + 2049 + r) * 64 + c] = 0;
  }
  for (int i = tid; i < 64 * 63; i += 256) {  // Vt pad cols 2049..2111
    int d = i / 63, c = i % 63;
    Vt[((size_t)bh * 64 + d) * NKP_ + 2049 + c] = 0;
  }
  if (bh == 0) {
    int* cnts = (int*)&shf[0][0];
    if (tid < 4) cnts[tid] = 0;
    __syncthreads();
    int c0 = 0, c1 = 0, c2 = 0, c3 = 0;
    for (int i = tid; i < B_ * N_; i += 256) {
      int z = (mask[i] == 0);
      int b = i >> 11;
      if (b == 0) c0 += z; else if (b == 1) c1 += z; else if (b == 2) c2 += z; else c3 += z;
    }
    atomicAdd(&cnts[0], c0); atomicAdd(&cnts[1], c1);
    atomicAdd(&cnts[2], c2); atomicAdd(&cnts[3], c3);
    __syncthreads();
    if (tid == 0) {
      float mw = 0.f;
      for (int i = 0; i < DH_; ++i) mw = fmaxf(mw, fabsf(qs[i] * ksc[i]));
      float cbias = -8.0f * mw * 1.4426950408889634f;
      cb[0] = cbias;
      float e = __builtin_amdgcn_exp2f(cbias);  // same HW instr as attn's exp2
#pragma unroll
      for (int b = 0; b < 4; ++b) cb[1 + b] = (float)(cnts[b] + 63) * e;
    }
  }
}

// ------------- fused QKV GEMM, 256x256 tile, 8 waves, dbuf 128 KB LDS -------------
// MEASURED-BEST (R10/R16/R18/R20: ~104.5-105 us).  Design space closed:
// blocking 1-tile 104.8 / counted 1-deep 108 / counted 3-deep 108-111 /
// 2blk-TLP 108.9 / blocking 2-tile 114.5.  Binder = staging drain; escape
// needs the full m201 8-phase interleave (out of headless risk budget).
__global__ __launch_bounds__(512, 1) void gemm_qkv(const u16* __restrict__ A,
                                                   const u16* __restrict__ Bt,
                                                   u16* __restrict__ Qo,
                                                   u16* __restrict__ Kb,
                                                   u16* __restrict__ Vt,
                                                   const float* __restrict__ qs,
                                                   const float* __restrict__ ksc,
                                                   const int* __restrict__ Mask) {
  __shared__ __attribute__((aligned(16))) u16 dsm[65536];  // 128 KB: [buf][A|B][256*64]
  int bx = blockIdx.x, by = blockIdx.y;
  int tid = threadIdx.x, lane = tid & 63, wid = tid >> 6;  // wid 0..7
  int wr = wid >> 2, wc = wid & 3;
  int m0 = bx * 256, n0 = by * 256;
  int wm = wr * 128, wn = wc * 64;
  int la = lane & 15, hi = lane >> 4, crow = hi * 4;
  int sr = lane >> 3;
  int scz = ((lane & 7) ^ (lane >> 3)) * 8;  // pre-swizzled source column (elems)
  f32x4 acc[8][4] = {};

#define QSTAGE(buf, kt)                                                        \
  do {                                                                         \
    int k0_ = (kt) * 64;                                                       \
    u16* ab_ = dsm + (buf) * 32768;                                            \
    _Pragma("unroll")                                                          \
    for (int r4 = 0; r4 < 4; ++r4) {                                           \
      int r_ = r4 * 64 + wid * 8;       /* wave-uniform row base */            \
      load_lds16(A  + (size_t)(m0 + r_ + sr) * 1024 + k0_ + scz, ab_ + r_ * 64); \
      load_lds16(Bt + (size_t)(n0 + r_ + sr) * 1024 + k0_ + scz, ab_ + 16384 + r_ * 64); \
    }                                                                          \
  } while (0)

  QSTAGE(0, 0);

  for (int kt = 0; kt < 16; ++kt) {
    int buf = kt & 1;
    __syncthreads();  // drains vmcnt: tile kt present; tile kt-1 fully consumed
    if (kt + 1 < 16) QSTAGE(buf ^ 1, kt + 1);
    const u16* a_l = dsm + buf * 32768;
    const u16* b_l = a_l + 16384;
    __builtin_amdgcn_s_setprio(1);
#pragma unroll
    for (int s = 0; s < 2; ++s) {
      int slotbase = s * 4 + hi;  // k-group; LDS slot = group ^ (row&7), row&7 = la&7
      bf16x8 bfr[4];
#pragma unroll
      for (int nf = 0; nf < 4; ++nf)
        bfr[nf] = *(const bf16x8*)&b_l[(wn + nf * 16 + la) * 64 + ((slotbase ^ (la & 7)) * 8)];
#pragma unroll
      for (int mf = 0; mf < 8; ++mf) {
        bf16x8 af = *(const bf16x8*)&a_l[(wm + mf * 16 + la) * 64 + ((slotbase ^ (la & 7)) * 8)];
#pragma unroll
        for (int nf = 0; nf < 4; ++nf)
          acc[mf][nf] = __builtin_amdgcn_mfma_f32_16x16x32_bf16(af, bfr[nf], acc[mf][nf], 0, 0, 0);
      }
    }
    __builtin_amdgcn_s_setprio(0);
  }
#undef QSTAGE

  int ccol = la;
  if (by < 4) {
    // ---- q: fused per-head l2norm * qs (wave cols = one head) ----
    float qsv[4];
#pragma unroll
    for (int nf = 0; nf < 4; ++nf) qsv[nf] = qs[nf * 16 + ccol];
#pragma unroll
    for (int mf = 0; mf < 8; ++mf) {
      float invr[4];
#pragma unroll
      for (int r = 0; r < 4; ++r) {
        float ss = 0.f;
#pragma unroll
        for (int nf = 0; nf < 4; ++nf) ss += acc[mf][nf][r] * acc[mf][nf][r];
#pragma unroll
        for (int off = 1; off < 16; off <<= 1) ss += __shfl_xor(ss, off, 64);
        invr[r] = 1.0f / fmaxf(sqrtf(ss), 1e-12f);
      }
#pragma unroll
      for (int nf = 0; nf < 4; ++nf) {
        int rr = m0 + wm + mf * 16 + crow;
        int cc = by * 256 + wn + nf * 16 + ccol;
#pragma unroll
        for (int r = 0; r < 4; ++r)
          Qo[(size_t)(rr + r) * 1024 + cc] = f2bf(acc[mf][nf][r] * invr[r] * qsv[nf]);
      }
    }
    return;
  }

  int rr0 = m0 + wm;          // wave's 128 rows; never crosses batch boundary
  int b = rr0 >> 11;
  int seq0 = rr0 & 2047;
  const int* mrow = Mask + b * N_ + seq0;
  if (by < 8) {
    // ---- K: fused l2norm * ksc, masked rows zeroed -> Kb[bh][key][64] ----
    int h = (by - 4) * 4 + wc;
    float kscv[4];
#pragma unroll
    for (int nf = 0; nf < 4; ++nf) kscv[nf] = ksc[nf * 16 + ccol];
    u16* kb = Kb + ((size_t)(b * 16 + h) * NKP_) * 64;
#pragma unroll
    for (int mf = 0; mf < 8; ++mf) {
      float invr[4]; int mvv[4];
#pragma unroll
      for (int r = 0; r < 4; ++r) {
        float ss = 0.f;
#pragma unroll
        for (int nf = 0; nf < 4; ++nf) ss += acc[mf][nf][r] * acc[mf][nf][r];
#pragma unroll
        for (int off = 1; off < 16; off <<= 1) ss += __shfl_xor(ss, off, 64);
        invr[r] = 1.0f / fmaxf(sqrtf(ss), 1e-12f);
        mvv[r] = mrow[mf * 16 + crow + r];  // row-uniform -> broadcast load
      }
#pragma unroll
      for (int nf = 0; nf < 4; ++nf)
#pragma unroll
        for (int r = 0; r < 4; ++r)
          kb[(size_t)(seq0 + mf * 16 + crow + r) * 64 + nf * 16 + ccol] =
              f2bf(mvv[r] ? acc[mf][nf][r] * invr[r] * kscv[nf] : 0.f);
    }
  } else {
    // ---- V: mask-zero, transpose 128key x 64d wave tile via LDS -> Vt ----
    int h = (by - 8) * 4 + wc;
    __syncthreads();                 // all waves done reading gemm tiles
    u16* tw = dsm + wid * 8192;      // per-wave [64 d][128 key], key-slot swizzled
#pragma unroll
    for (int mf = 0; mf < 8; ++mf) {
      int mvv[4];
#pragma unroll
      for (int r = 0; r < 4; ++r) mvv[r] = mrow[mf * 16 + crow + r];
#pragma unroll
      for (int nf = 0; nf < 4; ++nf) {
        int d = nf * 16 + ccol;
#pragma unroll
        for (int r = 0; r < 4; ++r) {
          int key = mf * 16 + crow + r;
          tw[d * 128 + ((((key >> 3) ^ (d & 7)) << 3) | (key & 7))] =
              f2bf(mvv[r] ? acc[mf][nf][r] : 0.f);
        }
      }
    }
    u16* vb = Vt + ((size_t)(b * 16 + h) * 64) * NKP_;
    int key0 = seq0;                 // wave's 128 keys start at seq0
    int dr = lane >> 3, kc8 = (lane & 7);
#pragma unroll
    for (int j = 0; j < 8; ++j) {
      int d = j * 8 + dr;
#pragma unroll
      for (int half = 0; half < 2; ++half) {
        int kslot = kc8 + half * 8;  // key-group 0..15 (keys kslot*8..+7)
        bf16x8 vv = *(const bf16x8*)&tw[d * 128 + (((kslot ^ (d & 7)) & 15) * 8)];
        *(bf16x8*)(vb + (size_t)d * NKP_ + key0 + kslot * 8) = vv;
      }
    }
  }
}

// ===== 128^2-tile blocking GEMM body (m97 structure) for the out-proj =====
#define GEMM_BODY(A, Bt)                                                       \
  int tid = threadIdx.x, lane = tid & 63, wid = tid >> 6;                      \
  int m0 = blockIdx.x * 128, n0 = blockIdx.y * 128;                            \
  int wm = (wid >> 1) * 64, wn = (wid & 1) * 64;                               \
  int sr = lane >> 3;                                                          \
  int scz = ((lane & 7) ^ (lane >> 3)) * 8;                                    \
  int la = lane & 15, lk = (lane >> 4) * 8;                                    \
  int swz = (la & 7) * 8;                                                      \
  f32x4 acc[4][4] = {};                                                        \
  for (int kt = 0; kt < 16; ++kt) {                                            \
    int k0_ = kt * 64;                                                         \
    __syncthreads();                                                           \
    _Pragma("unroll")                                                          \
    for (int i_ = 0; i_ < 4; ++i_) {                                           \
      int r_ = i_ * 32 + wid * 8;                                              \
      load_lds16(A + (size_t)(m0 + r_ + sr) * 1024 + k0_ + scz, &a_sm[r_ * 64]); \
      load_lds16(Bt + (size_t)(n0 + r_ + sr) * 1024 + k0_ + scz, &b_sm[r_ * 64]); \
    }                                                                          \
    __syncthreads();                                                           \
    _Pragma("unroll")                                                          \
    for (int s = 0; s < 2; ++s) {                                              \
      bf16x8 af[4], bfr[4];                                                    \
      _Pragma("unroll")                                                        \
      for (int mf = 0; mf < 4; ++mf)                                           \
        af[mf] = *(const bf16x8*)&a_sm[(wm + mf * 16 + la) * 64 + ((s * 32 + lk) ^ swz)]; \
      _Pragma("unroll")                                                        \
      for (int nf = 0; nf < 4; ++nf)                                           \
        bfr[nf] = *(const bf16x8*)&b_sm[(wn + nf * 16 + la) * 64 + ((s * 32 + lk) ^ swz)]; \
      _Pragma("unroll")                                                        \
      for (int mf = 0; mf < 4; ++mf)                                           \
        _Pragma("unroll")                                                      \
        for (int nf = 0; nf < 4; ++nf)                                         \
          acc[mf][nf] = __builtin_amdgcn_mfma_f32_16x16x32_bf16(af[mf], bfr[nf], acc[mf][nf], 0, 0, 0); \
    }                                                                          \
  }                                                                            \
  int crow = (lane >> 4) * 4, ccol = lane & 15;

// ------------- out-proj GEMM: attn_out x woT -> f32 d_out -------------
__global__ __launch_bounds__(256) void gemm_out(const u16* __restrict__ A,
                                                const u16* __restrict__ Bt,
                                                float* __restrict__ C) {
  __shared__ __attribute__((aligned(16))) u16 sm[2 * 128 * 64];  // 32 KB
  u16* a_sm = sm;
  u16* b_sm = sm + 128 * 64;
  GEMM_BODY(A, Bt)
#pragma unroll
  for (int mf = 0; mf < 4; ++mf)
#pragma unroll
    for (int nf = 0; nf < 4; ++nf) {
      int rr = m0 + wm + mf * 16 + crow;
      int cc = n0 + wn + nf * 16 + ccol;
#pragma unroll
      for (int r = 0; r < 4; ++r) C[(size_t)(rr + r) * 1024 + cc] = acc[mf][nf][r];
    }
}

// ------------- flash attention (measured best: ~90 us, dbuf K/V) -------------
// grid (bh=64, qtile=8), 8 waves/block (512 thr), 32 q-rows/wave, 64-key tiles.
// LDS 64 KB -> 2 blocks/CU -> 512 slots = grid: single full round.  Swapped
// QK^T; MASKLESS fixed-max softmax in exp2 domain (masked keys K=0,V=0; mass
// cb[1+b] subtracted in epilogue).  b64 P-writes; XOR-swizzled LDS; 2-phase
// dbuf; T5 setprio; kt loop unrolled x2.  R19 A/B: 3-blocks/CU single-buffer
// variant was null -> attn is intra-wave dependency-chain-bound; dbuf kept.
__global__ __launch_bounds__(512) void attn_kernel(const u16* __restrict__ Q,
                                                   const u16* __restrict__ Kb,
                                                   const u16* __restrict__ Vt,
                                                   const float* __restrict__ cb,
                                                   u16* __restrict__ O) {
  __shared__ __attribute__((aligned(16))) u16 k_sm[2][64 * 64];  // [key][d], swizzled
  __shared__ __attribute__((aligned(16))) u16 v_sm[2][64 * 64];  // [d][key], swizzled
  __shared__ __attribute__((aligned(16))) u16 p_sm[8][32 * 64];  // per-wave P [q][key], swizzled
  int tid = threadIdx.x, lane = tid & 63, wid = tid >> 6;        // wid 0..7
  int bh = blockIdx.x, b = bh >> 4, h = bh & 15;
  int q0 = blockIdx.y * 256 + wid * 32;
  int la = lane & 15, lk = (lane >> 4) * 8, crow = (lane >> 4) * 4;
  int swz = (la & 7) * 8;                           // read-side XOR (row = x*16+la)
  int sr = lane >> 3;
  int scz = ((lane & 7) ^ (lane >> 3)) * 8;         // pre-swizzled source column

  bf16x8 aq[2][2];
#pragma unroll
  for (int qb = 0; qb < 2; ++qb) {
    const u16* qrow = Q + ((size_t)(b * N_) + q0 + qb * 16 + la) * D_ + h * DH_;
#pragma unroll
    for (int s = 0; s < 2; ++s) aq[qb][s] = *(const bf16x8*)(qrow + s * 32 + lk);
  }
  float l[2] = {0.f, 0.f};                          // per-lane partial sums (q = la)
  f32x4 o[2][4] = {};
  const u16* Kbh = Kb + (size_t)bh * NKP_ * 64;
  const u16* Vbh = Vt + (size_t)bh * 64 * NKP_;
  const float C1 = 11.541560327111707f;             // 8*log2(e)
  const float cbias = cb[0];                        // -8*max|qs*ks|*log2(e)
  const float lsub = cb[1 + b];                     // zero-key l mass to remove

#define STAGE(bb, kt)                                                          \
  do {                                                                         \
    int key0_ = (kt) * 64;                                                     \
    int r_ = wid * 8;                                                          \
    load_lds16(Kbh + (size_t)(key0_ + r_ + sr) * 64 + scz, &k_sm[bb][r_ * 64]); \
    load_lds16(Vbh + (size_t)(r_ + sr) * NKP_ + key0_ + scz, &v_sm[bb][r_ * 64]); \
  } while (0)

  STAGE(0, 0);

#pragma unroll 2
  for (int kt = 0; kt < NKT_; ++kt) {
    int bb = kt & 1;
    __syncthreads();  // drains vmcnt: STAGE(kt) complete; prev-tile reads done
    if (kt + 1 < NKT_) STAGE(bb ^ 1, kt + 1);

    f32x4 sacc[2][4] = {};
    __builtin_amdgcn_s_setprio(1);
#pragma unroll
    for (int nf = 0; nf < 4; ++nf) {
      bf16x8 bk0 = *(const bf16x8*)&k_sm[bb][(nf * 16 + la) * 64 + (lk ^ swz)];
      bf16x8 bk1 = *(const bf16x8*)&k_sm[bb][(nf * 16 + la) * 64 + ((32 + lk) ^ swz)];
#pragma unroll
      for (int qb = 0; qb < 2; ++qb) {
        sacc[qb][nf] = __builtin_amdgcn_mfma_f32_16x16x32_bf16(bk0, aq[qb][0], sacc[qb][nf], 0, 0, 0);
        sacc[qb][nf] = __builtin_amdgcn_mfma_f32_16x16x32_bf16(bk1, aq[qb][1], sacc[qb][nf], 0, 0, 0);
      }
    }
    __builtin_amdgcn_s_setprio(0);

#pragma unroll
    for (int nf = 0; nf < 4; ++nf) {
      int key = nf * 16 + crow;
#pragma unroll
      for (int qb = 0; qb < 2; ++qb) {
        float p0 = __builtin_amdgcn_exp2f(fmaf(sacc[qb][nf][0], C1, cbias));
        float p1 = __builtin_amdgcn_exp2f(fmaf(sacc[qb][nf][1], C1, cbias));
        float p2 = __builtin_amdgcn_exp2f(fmaf(sacc[qb][nf][2], C1, cbias));
        float p3 = __builtin_amdgcn_exp2f(fmaf(sacc[qb][nf][3], C1, cbias));
        l[qb] += (p0 + p1) + (p2 + p3);
        uint2 pw;
        pw.x = cvtpk(p0, p1);
        pw.y = cvtpk(p2, p3);
        *(uint2*)&p_sm[wid][(qb * 16 + la) * 64 + (key ^ swz)] = pw;
      }
    }

    __builtin_amdgcn_s_setprio(1);
#pragma unroll
    for (int s = 0; s < 2; ++s) {
      bf16x8 bv[4];
#pragma unroll
      for (int dt = 0; dt < 4; ++dt)
        bv[dt] = *(const bf16x8*)&v_sm[bb][(dt * 16 + la) * 64 + ((s * 32 + lk) ^ swz)];
#pragma unroll
      for (int qb = 0; qb < 2; ++qb) {
        bf16x8 ap = *(const bf16x8*)&p_sm[wid][(qb * 16 + la) * 64 + ((s * 32 + lk) ^ swz)];
#pragma unroll
        for (int dt = 0; dt < 4; ++dt)
          o[qb][dt] = __builtin_amdgcn_mfma_f32_16x16x32_bf16(ap, bv[dt], o[qb][dt], 0, 0, 0);
      }
    }
    __builtin_amdgcn_s_setprio(0);
  }
#undef STAGE

#pragma unroll
  for (int qb = 0; qb < 2; ++qb) {
    l[qb] += __shfl_xor(l[qb], 16, 64);
    l[qb] += __shfl_xor(l[qb], 32, 64);
#pragma unroll
    for (int r = 0; r < 4; ++r) {
      float lq = __shfl(l[qb], crow + r, 64) - lsub;  // remove zeroed-key mass
      float inv = 1.0f / lq;
      int n = q0 + qb * 16 + crow + r;
      u16* ob = O + ((size_t)(b * N_) + n) * D_ + h * DH_;
#pragma unroll
      for (int dt = 0; dt < 4; ++dt) ob[dt * 16 + la] = f2bf(o[qb][dt][r] * inv);
    }
  }
}

extern "C" void kernel_launch(void* const* d_in, const int* in_sizes, int n_in,
                              void* d_out, int out_size, void* d_ws, size_t ws_size,
                              hipStream_t stream) {
  (void)in_sizes; (void)n_in; (void)out_size; (void)ws_size;
  const float* x     = (const float*)d_in[0];
  const int*   mask  = (const int*)d_in[1];
  const float* gamma = (const float*)d_in[2];
  const float* wq    = (const float*)d_in[3];
  const float* wkv   = (const float*)d_in[4];
  const float* nkv   = (const float*)d_in[5];
  const float* qs    = (const float*)d_in[6];
  const float* ksc   = (const float*)d_in[7];
  const float* wo    = (const float*)d_in[8];

  // workspace layout (~59 MiB)
  char* ws   = (char*)d_ws;
  u16* xn    = (u16*)(ws);                        // 16 MiB; reused as attn_out
  u16* wqkvT = (u16*)(ws + (16ull << 20));        // 6 MiB: wqT[1024] + wkvT[2048] rows
  u16* woT   = (u16*)(ws + (22ull << 20));        // 2 MiB
  u16* Kb    = (u16*)(ws + (24ull << 20));        // 16.5 MiB
  u16* Vt    = (u16*)(ws + (41ull << 20));        // 16.5 MiB
  float* cb  = (float*)(ws + (58ull << 20));      // 5 floats
  u16* q_tmp = (u16*)d_out;                       // 16 MiB scratch inside 32 MiB d_out
  u16* attn_out = xn;                             // alias: xn dead after qkv GEMM

  pre_kernel<<<12352, 256, 0, stream>>>(x, gamma, xn, wq, wkv, wo, wqkvT, woT,
                                        mask, qs, ksc, nkv, Kb, Vt, cb);
  gemm_qkv<<<dim3(32, 12), 512, 0, stream>>>(xn, wqkvT, q_tmp, Kb, Vt, qs, ksc, mask);
  attn_kernel<<<dim3(64, 8), 512, 0, stream>>>(q_tmp, Kb, Vt, cb, attn_out);
  gemm_out<<<dim3(64, 8), 256, 0, stream>>>(attn_out, woT, (float*)d_out);
}